// Round 6
// baseline (1213.367 us; speedup 1.0000x reference)
//
#include <hip/hip_runtime.h>
#include <hip/hip_bf16.h>
#include <math.h>

#define BB 32
#define TT 4096
#define DD 256
#define LL 2
#define NC 64          // number of time chunks for the scan
#define CH 64          // chunk length (NC*CH == TT)
#define MM (BB*TT)     // 131072 rows
#define EPSV 1e-5f

typedef __bf16 bf16;
typedef __attribute__((ext_vector_type(8))) __bf16 bf16x8;
typedef __attribute__((ext_vector_type(4))) __bf16 bf16x4;
typedef __attribute__((ext_vector_type(2))) __bf16 bf16x2;
typedef __attribute__((ext_vector_type(4))) float f32x4;

// ---------------------------------------------------------------------------
__device__ __forceinline__ float decay_of(int d) {
    const float l0 = 2.302585092994046f;      // log(10)
    const float l1 = 7.6009024595420815f;     // log(2000)
    float lt = l0 + (float)d * (l1 - l0) * (1.0f / 255.0f);
    return expf(-expf(-lt));
}
__device__ __forceinline__ float silu_f(float v) { return v / (1.0f + expf(-v)); }

// ---------------------------------------------------------------------------
// one-shot fp32 -> bf16 conversion of all three weight tensors
__global__ void cvtw_k(const float* __restrict__ we, const float* __restrict__ wi,
                       const float* __restrict__ wo, bf16* __restrict__ de,
                       bf16* __restrict__ di, bf16* __restrict__ dk)
{
    int i = blockIdx.x * 1024 + threadIdx.x;            // 458752 total
    if (i < 65536)            de[i] = (bf16)we[i];
    else if (i < 327680)      di[i - 65536] = (bf16)wi[i - 65536];
    else if (i < 458752)      dk[i - 327680] = (bf16)wo[i - 327680];
}

// ---------------------------------------------------------------------------
// GEMM: C[64 rows x 256 cols] = A[M x 256] * W^T + bias, one tile/block.
// 256 threads / 4 waves, wave owns 16 A-rows x 256 cols.
// Swapped-operand MFMA: D "row" = W-col (lane>>4)*4+i, D "col" = A-row (lane&15).
// K-split staging through a fixed 32 KiB LDS buffer (4 stages x 8 k-chunks):
// 4 blocks/CU (LDS-limited), launch_bounds(256,4) -> 128-VGPR cap, NO spill
// (round-5 lesson: MINW=5's 102-reg cap spilled; round-2: 1024thr spilled).
// LDS fragment-major + XOR swizzle: unit idx = kc_local*256 + (n ^ (kcg&15));
// staging writes and MFMA reads both spread over all 32 banks (0 conflicts,
// verified round 4/5).
// EPI 1: rowwise LN+ReLU -> O0 bf16     (encoder)
// EPI 2: O0 += acc (in-place bf16 h)
// EPI 3: y=0 -> O0 plain (x half); y=1 -> silu -> O1 (z half)   (in_proj)
// EPI 4: acc += O0(h); rowwise LN -> Of fp32   (out_proj l1 + final LN)
template<int SRCF32, int EPI>
__global__ __launch_bounds__(256, 4)
void gemm_k(const void* __restrict__ Asrc,
            const bf16* __restrict__ W,
            const float* __restrict__ bias,
            const float* __restrict__ g1, const float* __restrict__ b1,
            bf16* __restrict__ O0, bf16* __restrict__ O1,
            float* __restrict__ Of)
{
    constexpr int NT = 16;                    // 256 cols / 16
    constexpr int KCS = 8;                    // 16B k-chunks per stage
    constexpr int NSTAGE = 4;                 // stages to cover K=256
    constexpr int KKS = 2;                    // kk (32-wide K steps) per stage
    __shared__ bf16x8 ldsW[2048];             // 32 KiB

    const int tid = threadIdx.x;
    const int colblk = blockIdx.y * 256;
    const bf16* Wblk = W + (size_t)colblk * 256;

    const int wave = tid >> 6, lane = tid & 63;
    const int r = lane & 15, g4 = lane >> 4;
    const int c4 = g4 * 4;                    // first of 4 consecutive cols
    const size_t row = (size_t)blockIdx.x * 64 + wave * 16 + r;

    // ---- issue A-fragment loads first (latency hides under staging) ----
    bf16x8 af[8];
    if (SRCF32) {
        const float* ap0 = (const float*)Asrc + row * 256;
        #pragma unroll
        for (int kk = 0; kk < 8; ++kk) {
            const float* ap = ap0 + kk * 32 + g4 * 8;
            float4 f0 = *(const float4*)ap;
            float4 f1 = *(const float4*)(ap + 4);
            bf16x8 t;
            t[0]=(bf16)f0.x; t[1]=(bf16)f0.y; t[2]=(bf16)f0.z; t[3]=(bf16)f0.w;
            t[4]=(bf16)f1.x; t[5]=(bf16)f1.y; t[6]=(bf16)f1.z; t[7]=(bf16)f1.w;
            af[kk] = t;
        }
    } else {
        const bf16* ap0 = (const bf16*)Asrc + row * 256;
        #pragma unroll
        for (int kk = 0; kk < 8; ++kk)
            af[kk] = *(const bf16x8*)(ap0 + kk * 32 + g4 * 8);
    }

    f32x4 acc[NT];
    #pragma unroll
    for (int nt = 0; nt < NT; ++nt) {
        float4 bv = *(const float4*)(bias + colblk + nt * 16 + c4);
        acc[nt] = (f32x4){bv.x, bv.y, bv.z, bv.w};
    }

    // ---- K-split staged main loop ----
    #pragma unroll
    for (int s = 0; s < NSTAGE; ++s) {
        if (s) __syncthreads();               // readers of previous stage done
        const int sBase = s * KCS;
        #pragma unroll
        for (int i = 0; i < 8; ++i) {         // 2048 units / 256 threads
            int idx = tid + i * 256;
            int n   = idx / KCS;              // W-col within tile (0..255)
            int kc  = idx % KCS;              // local 16B k-chunk
            int kcg = sBase + kc;             // global k-chunk
            ldsW[kc * 256 + (n ^ (kcg & 15))] =
                *(const bf16x8*)(Wblk + n * 256 + kcg * 8);
        }
        __syncthreads();
        #pragma unroll
        for (int kk = s * KKS; kk < (s + 1) * KKS; ++kk) {
            const int kcg = kk * 4 + g4;
            const int base = (kcg - sBase) * 256;
            const int swz = kcg & 15;
            #pragma unroll
            for (int nt = 0; nt < NT; ++nt) {
                bf16x8 bfr = ldsW[base + ((nt * 16 + r) ^ swz)];
                acc[nt] = __builtin_amdgcn_mfma_f32_16x16x32_bf16(bfr, af[kk], acc[nt], 0, 0, 0);
            }
        }
    }

    if (EPI == 1) {                       // LN + ReLU
        float s = 0.f, q = 0.f;
        #pragma unroll
        for (int nt = 0; nt < NT; ++nt)
            #pragma unroll
            for (int i = 0; i < 4; ++i) { float v = acc[nt][i]; s += v; q += v * v; }
        s += __shfl_xor(s, 16); q += __shfl_xor(q, 16);
        s += __shfl_xor(s, 32); q += __shfl_xor(q, 32);
        float mean = s * (1.0f / 256.0f);
        float rstd = rsqrtf(q * (1.0f / 256.0f) - mean * mean + EPSV);
        #pragma unroll
        for (int nt = 0; nt < NT; ++nt) {
            float4 gg = *(const float4*)(g1 + nt * 16 + c4);
            float4 bb = *(const float4*)(b1 + nt * 16 + c4);
            bf16x4 st;
            st[0] = (bf16)fmaxf((acc[nt][0] - mean) * rstd * gg.x + bb.x, 0.f);
            st[1] = (bf16)fmaxf((acc[nt][1] - mean) * rstd * gg.y + bb.y, 0.f);
            st[2] = (bf16)fmaxf((acc[nt][2] - mean) * rstd * gg.z + bb.z, 0.f);
            st[3] = (bf16)fmaxf((acc[nt][3] - mean) * rstd * gg.w + bb.w, 0.f);
            *(bf16x4*)(O0 + row * 256 + nt * 16 + c4) = st;
        }
    } else if (EPI == 2) {                // residual in-place
        #pragma unroll
        for (int nt = 0; nt < NT; ++nt) {
            bf16* p = O0 + row * 256 + nt * 16 + c4;
            bf16x4 hv = *(const bf16x4*)p;
            bf16x4 st;
            #pragma unroll
            for (int i = 0; i < 4; ++i) st[i] = (bf16)(acc[nt][i] + (float)hv[i]);
            *(bf16x4*)p = st;
        }
    } else if (EPI == 3) {                // in_proj: y=0 x-half plain, y=1 z-half silu
        const int dosilu = (colblk >= 256);
        bf16* dst = dosilu ? O1 : O0;
        #pragma unroll
        for (int nt = 0; nt < NT; ++nt) {
            bf16x4 st;
            #pragma unroll
            for (int i = 0; i < 4; ++i) {
                float v = acc[nt][i];
                if (dosilu) v = silu_f(v);
                st[i] = (bf16)v;
            }
            *(bf16x4*)(dst + row * 256 + nt * 16 + c4) = st;
        }
    } else {                              // EPI 4: +h, LN, fp32 out
        #pragma unroll
        for (int nt = 0; nt < NT; ++nt) {
            bf16x4 hv = *(const bf16x4*)(O0 + row * 256 + nt * 16 + c4);
            #pragma unroll
            for (int i = 0; i < 4; ++i) acc[nt][i] += (float)hv[i];
        }
        float s = 0.f, q = 0.f;
        #pragma unroll
        for (int nt = 0; nt < NT; ++nt)
            #pragma unroll
            for (int i = 0; i < 4; ++i) { float v = acc[nt][i]; s += v; q += v * v; }
        s += __shfl_xor(s, 16); q += __shfl_xor(q, 16);
        s += __shfl_xor(s, 32); q += __shfl_xor(q, 32);
        float mean = s * (1.0f / 256.0f);
        float rstd = rsqrtf(q * (1.0f / 256.0f) - mean * mean + EPSV);
        #pragma unroll
        for (int nt = 0; nt < NT; ++nt) {
            float4 gg = *(const float4*)(g1 + nt * 16 + c4);
            float4 bb = *(const float4*)(b1 + nt * 16 + c4);
            float4 o;
            o.x = (acc[nt][0] - mean) * rstd * gg.x + bb.x;
            o.y = (acc[nt][1] - mean) * rstd * gg.y + bb.y;
            o.z = (acc[nt][2] - mean) * rstd * gg.z + bb.z;
            o.w = (acc[nt][3] - mean) * rstd * gg.w + bb.w;
            *(float4*)(Of + row * 256 + nt * 16 + c4) = o;
        }
    }
}

// ---------------------------------------------------------------------------
// pass 1: conv(K=4)+SiLU+local EMA inside a 64-step chunk; emit chunk-final only.
__global__ void pass1_k(const bf16* __restrict__ xc,
                        const float* __restrict__ cw, const float* __restrict__ cb,
                        float* __restrict__ cfin)
{
    const int d0 = threadIdx.x * 2;
    const int c = blockIdx.x, b = blockIdx.y;
    const int t0 = c * CH;
    const float w00=cw[d0*4+0], w01=cw[d0*4+1], w02=cw[d0*4+2], w03=cw[d0*4+3];
    const float w10=cw[d0*4+4], w11=cw[d0*4+5], w12=cw[d0*4+6], w13=cw[d0*4+7];
    const float bb0 = cb[d0], bb1 = cb[d0+1];
    const float a0 = decay_of(d0), a1 = decay_of(d0+1);
    const size_t base = (size_t)b * TT * 256 + d0;
    float x0m1=0,x0m2=0,x0m3=0, x1m1=0,x1m2=0,x1m3=0;
    if (t0 >= 1) { bf16x2 p = *(const bf16x2*)(xc + base + (size_t)(t0-1)*256); x0m1=(float)p[0]; x1m1=(float)p[1]; }
    if (t0 >= 2) { bf16x2 p = *(const bf16x2*)(xc + base + (size_t)(t0-2)*256); x0m2=(float)p[0]; x1m2=(float)p[1]; }
    if (t0 >= 3) { bf16x2 p = *(const bf16x2*)(xc + base + (size_t)(t0-3)*256); x0m3=(float)p[0]; x1m3=(float)p[1]; }
    float h0 = 0.f, h1 = 0.f;
    for (int t = t0; t < t0 + CH; ++t) {
        bf16x2 p = *(const bf16x2*)(xc + base + (size_t)t * 256);
        float xa = (float)p[0], xb = (float)p[1];
        float v0 = w03*xa + w02*x0m1 + w01*x0m2 + w00*x0m3 + bb0;
        float v1 = w13*xb + w12*x1m1 + w11*x1m2 + w10*x1m3 + bb1;
        h0 = a0*h0 + (1.f-a0)*silu_f(v0);
        h1 = a1*h1 + (1.f-a1)*silu_f(v1);
        x0m3=x0m2; x0m2=x0m1; x0m1=xa;
        x1m3=x1m2; x1m2=x1m1; x1m1=xb;
    }
    *(float2*)(cfin + ((size_t)b*NC + c)*256 + d0) = make_float2(h0, h1);
}

// pass 2: per-(b,d) carry recurrence over the 64 chunk finals.
__global__ void scan2_k(const float* __restrict__ cfin, float* __restrict__ cin)
{
    const int d = threadIdx.x, b = blockIdx.x;
    float a = decay_of(d);
    float aC = a;
    #pragma unroll
    for (int j = 0; j < 6; ++j) aC *= aC;   // a^64
    float H = 0.f;
    for (int c = 0; c < NC; ++c) {
        size_t o = ((size_t)b * NC + c) * 256 + d;
        cin[o] = H;
        H = aC * H + cfin[o];
    }
}

// pass 3: recompute conv+SiLU+EMA with exact carry-in; u = hi * sz; u aliases sz.
__global__ void pass3_k(const bf16* __restrict__ xc, const float* __restrict__ cin,
                        const float* __restrict__ cw, const float* __restrict__ cb,
                        bf16* __restrict__ szu)
{
    const int d0 = threadIdx.x * 2;
    const int c = blockIdx.x, b = blockIdx.y;
    const int t0 = c * CH;
    const float w00=cw[d0*4+0], w01=cw[d0*4+1], w02=cw[d0*4+2], w03=cw[d0*4+3];
    const float w10=cw[d0*4+4], w11=cw[d0*4+5], w12=cw[d0*4+6], w13=cw[d0*4+7];
    const float bb0 = cb[d0], bb1 = cb[d0+1];
    const float a0 = decay_of(d0), a1 = decay_of(d0+1);
    const size_t base = (size_t)b * TT * 256 + d0;
    float2 Hc = *(const float2*)(cin + ((size_t)b*NC + c)*256 + d0);
    float h0 = Hc.x, h1 = Hc.y;
    float x0m1=0,x0m2=0,x0m3=0, x1m1=0,x1m2=0,x1m3=0;
    if (t0 >= 1) { bf16x2 p = *(const bf16x2*)(xc + base + (size_t)(t0-1)*256); x0m1=(float)p[0]; x1m1=(float)p[1]; }
    if (t0 >= 2) { bf16x2 p = *(const bf16x2*)(xc + base + (size_t)(t0-2)*256); x0m2=(float)p[0]; x1m2=(float)p[1]; }
    if (t0 >= 3) { bf16x2 p = *(const bf16x2*)(xc + base + (size_t)(t0-3)*256); x0m3=(float)p[0]; x1m3=(float)p[1]; }
    for (int t = t0; t < t0 + CH; ++t) {
        bf16x2 p = *(const bf16x2*)(xc + base + (size_t)t * 256);
        float xa = (float)p[0], xb = (float)p[1];
        float v0 = w03*xa + w02*x0m1 + w01*x0m2 + w00*x0m3 + bb0;
        float v1 = w13*xb + w12*x1m1 + w11*x1m2 + w10*x1m3 + bb1;
        h0 = a0*h0 + (1.f-a0)*silu_f(v0);
        h1 = a1*h1 + (1.f-a1)*silu_f(v1);
        x0m3=x0m2; x0m2=x0m1; x0m1=xa;
        x1m3=x1m2; x1m2=x1m1; x1m1=xb;
        bf16* up = szu + base + (size_t)t * 256;
        bf16x2 sp = *(const bf16x2*)up;
        bf16x2 st;
        st[0] = (bf16)(h0 * (float)sp[0]);
        st[1] = (bf16)(h1 * (float)sp[1]);
        *(bf16x2*)up = st;
    }
}

// ---------------------------------------------------------------------------
extern "C" void kernel_launch(void* const* d_in, const int* in_sizes, int n_in,
                              void* d_out, int out_size, void* d_ws, size_t ws_size,
                              hipStream_t stream)
{
    (void)in_sizes; (void)n_in; (void)out_size;
    const float* x        = (const float*)d_in[0];
    const float* enc_w    = (const float*)d_in[1];
    const float* enc_b    = (const float*)d_in[2];
    const float* enc_ln_g = (const float*)d_in[3];
    const float* enc_ln_b = (const float*)d_in[4];
    const float* in_proj_w  = (const float*)d_in[5];
    const float* in_proj_b  = (const float*)d_in[6];
    const float* conv_w     = (const float*)d_in[7];
    const float* conv_b     = (const float*)d_in[8];
    const float* out_proj_w = (const float*)d_in[9];
    const float* out_proj_b = (const float*)d_in[10];
    const float* lnf_g      = (const float*)d_in[11];
    const float* lnf_b      = (const float*)d_in[12];

    // workspace: h (64MiB) | sz/u (64MiB) | wenc 128K | winp 512K | woutp 256K | cfin 2M | cin 2M
    if (ws_size < 139329536u) return;
    char* ws = (char*)d_ws;
    bf16*  h     = (bf16*)(ws);
    bf16*  szu   = (bf16*)(ws + 67108864);
    bf16*  wenc  = (bf16*)(ws + 134217728);
    bf16*  winp  = (bf16*)(ws + 134217728 + 131072);
    bf16*  woutp = (bf16*)(ws + 134217728 + 131072 + 524288);
    float* cfin  = (float*)(ws + 134217728 + 917504);
    float* cin   = (float*)(ws + 134217728 + 917504 + 2097152);
    bf16*  xc    = (bf16*)d_out;   // first 64 MiB of d_out as bf16 scratch

    cvtw_k<<<dim3(448), dim3(1024), 0, stream>>>(enc_w, in_proj_w, out_proj_w,
                                                 wenc, winp, woutp);

    dim3 gblk(256);
    // encoder: h = relu(LN(x @ enc_w^T + enc_b))
    gemm_k<1, 1><<<dim3(2048, 1), gblk, 0, stream>>>(x, wenc, enc_b,
                                                    enc_ln_g, enc_ln_b, h, nullptr, nullptr);
    for (int l = 0; l < LL; ++l) {
        // xc = h @ Wx^T + bx ; sz = silu(h @ Wz^T + bz)   [2 x 256-col y-blocks]
        gemm_k<0, 3><<<dim3(2048, 2), gblk, 0, stream>>>(h, winp + (size_t)l * 512 * 256,
                                                        in_proj_b + l * 512, nullptr, nullptr,
                                                        xc, szu, nullptr);
        pass1_k<<<dim3(NC, BB), dim3(128), 0, stream>>>(xc, conv_w + l * DD * 4,
                                                        conv_b + l * DD, cfin);
        scan2_k<<<dim3(BB), dim3(256), 0, stream>>>(cfin, cin);
        pass3_k<<<dim3(NC, BB), dim3(128), 0, stream>>>(xc, cin, conv_w + l * DD * 4,
                                                        conv_b + l * DD, szu);
        if (l == 0) {
            // h += u @ out_proj_w[0]^T + b
            gemm_k<0, 2><<<dim3(2048, 1), gblk, 0, stream>>>(szu, woutp,
                                                            out_proj_b, nullptr, nullptr,
                                                            h, nullptr, nullptr);
        } else {
            // out = LN(h + u @ out_proj_w[1]^T + b) -> fp32 d_out
            gemm_k<0, 4><<<dim3(2048, 1), gblk, 0, stream>>>(szu, woutp + (size_t)256 * 256,
                                                            out_proj_b + 256, lnf_g, lnf_b,
                                                            h, nullptr, (float*)d_out);
        }
    }
}

// Round 7
// 593.663 us; speedup vs baseline: 2.0439x; 2.0439x over previous
//
#include <hip/hip_runtime.h>
#include <hip/hip_bf16.h>
#include <math.h>

#define BB 32
#define TT 4096
#define DD 256
#define LL 2
#define NC 64          // number of time chunks for the scan
#define CH 64          // chunk length (NC*CH == TT)
#define MM (BB*TT)     // 131072 rows
#define EPSV 1e-5f

typedef __bf16 bf16;
typedef __attribute__((ext_vector_type(8))) __bf16 bf16x8;
typedef __attribute__((ext_vector_type(4))) __bf16 bf16x4;
typedef __attribute__((ext_vector_type(2))) __bf16 bf16x2;
typedef __attribute__((ext_vector_type(4))) float f32x4;

// ---------------------------------------------------------------------------
__device__ __forceinline__ float decay_of(int d) {
    const float l0 = 2.302585092994046f;      // log(10)
    const float l1 = 7.6009024595420815f;     // log(2000)
    float lt = l0 + (float)d * (l1 - l0) * (1.0f / 255.0f);
    return expf(-expf(-lt));
}
__device__ __forceinline__ float silu_f(float v) { return v / (1.0f + expf(-v)); }

// ---------------------------------------------------------------------------
// one-shot fp32 -> bf16 conversion of all three weight tensors
__global__ void cvtw_k(const float* __restrict__ we, const float* __restrict__ wi,
                       const float* __restrict__ wo, bf16* __restrict__ de,
                       bf16* __restrict__ di, bf16* __restrict__ dk)
{
    int i = blockIdx.x * 1024 + threadIdx.x;            // 458752 total
    if (i < 65536)            de[i] = (bf16)we[i];
    else if (i < 327680)      di[i - 65536] = (bf16)wi[i - 65536];
    else if (i < 458752)      dk[i - 327680] = (bf16)wo[i - 327680];
}

// ---------------------------------------------------------------------------
// GEMM: C[128 rows x 256 cols] = A[M x 256] * W^T + bias, one tile/block.
// 512 threads / 8 waves, wave owns 16 A-rows x 256 cols.
// Swapped-operand MFMA: D "row" = W-col (lane>>4)*4+i, D "col" = A-row (lane&15).
// VGPR DISCIPLINE (rounds 2/5/6 lesson): __launch_bounds__ 2nd arg MUST be <=2.
// Caps <=128 VGPR make hipcc sandbag to 64/48 regs and spill acc across the
// stage barriers (R6: 570MB writes vs 134 ideal). (512,2) gives natural ~92-120.
// K-split staging through a fixed 32 KiB LDS buffer (4 stages x 8 k-chunks):
// 2 blocks/CU co-resident (vs round-4's 1) so stage/barrier stalls overlap.
// LDS fragment-major + XOR swizzle: unit idx = kc_local*256 + (n ^ (kcg&15));
// staging writes and MFMA reads spread over banks (0 conflicts, verified R4-R6).
// EPI 1: rowwise LN+ReLU -> O0 bf16     (encoder)
// EPI 2: O0 += acc (in-place bf16 h)
// EPI 3: y=0 -> O0 plain (x half); y=1 -> silu -> O1 (z half)   (in_proj)
// EPI 4: acc += O0(h); rowwise LN -> Of fp32   (out_proj l1 + final LN)
template<int SRCF32, int EPI>
__global__ __launch_bounds__(512, 2)
void gemm_k(const void* __restrict__ Asrc,
            const bf16* __restrict__ W,
            const float* __restrict__ bias,
            const float* __restrict__ g1, const float* __restrict__ b1,
            bf16* __restrict__ O0, bf16* __restrict__ O1,
            float* __restrict__ Of)
{
    constexpr int NT = 16;                    // 256 cols / 16
    constexpr int KCS = 8;                    // 16B k-chunks per stage
    constexpr int NSTAGE = 4;                 // stages to cover K=256
    constexpr int KKS = 2;                    // kk (32-wide K steps) per stage
    __shared__ bf16x8 ldsW[2048];             // 32 KiB

    const int tid = threadIdx.x;
    const int colblk = blockIdx.y * 256;
    const bf16* Wblk = W + (size_t)colblk * 256;

    const int wave = tid >> 6, lane = tid & 63;
    const int r = lane & 15, g4 = lane >> 4;
    const int c4 = g4 * 4;                    // first of 4 consecutive cols
    const size_t row = (size_t)blockIdx.x * 128 + wave * 16 + r;

    // ---- issue A-fragment loads first (latency hides under staging) ----
    bf16x8 af[8];
    if (SRCF32) {
        const float* ap0 = (const float*)Asrc + row * 256;
        #pragma unroll
        for (int kk = 0; kk < 8; ++kk) {
            const float* ap = ap0 + kk * 32 + g4 * 8;
            float4 f0 = *(const float4*)ap;
            float4 f1 = *(const float4*)(ap + 4);
            bf16x8 t;
            t[0]=(bf16)f0.x; t[1]=(bf16)f0.y; t[2]=(bf16)f0.z; t[3]=(bf16)f0.w;
            t[4]=(bf16)f1.x; t[5]=(bf16)f1.y; t[6]=(bf16)f1.z; t[7]=(bf16)f1.w;
            af[kk] = t;
        }
    } else {
        const bf16* ap0 = (const bf16*)Asrc + row * 256;
        #pragma unroll
        for (int kk = 0; kk < 8; ++kk)
            af[kk] = *(const bf16x8*)(ap0 + kk * 32 + g4 * 8);
    }

    f32x4 acc[NT];
    #pragma unroll
    for (int nt = 0; nt < NT; ++nt) {
        float4 bv = *(const float4*)(bias + colblk + nt * 16 + c4);
        acc[nt] = (f32x4){bv.x, bv.y, bv.z, bv.w};
    }

    // ---- K-split staged main loop ----
    #pragma unroll
    for (int s = 0; s < NSTAGE; ++s) {
        if (s) __syncthreads();               // readers of previous stage done
        const int sBase = s * KCS;
        #pragma unroll
        for (int i = 0; i < 4; ++i) {         // 2048 units / 512 threads
            int idx = tid + i * 512;
            int n   = idx >> 3;               // W-col within tile (0..255)
            int kc  = idx & 7;                // local 16B k-chunk
            int kcg = sBase + kc;             // global k-chunk
            ldsW[kc * 256 + (n ^ (kcg & 15))] =
                *(const bf16x8*)(Wblk + n * 256 + kcg * 8);
        }
        __syncthreads();
        #pragma unroll
        for (int kk = s * KKS; kk < (s + 1) * KKS; ++kk) {
            const int kcg = kk * 4 + g4;
            const int base = (kcg - sBase) * 256;
            const int swz = kcg & 15;
            #pragma unroll
            for (int nt = 0; nt < NT; ++nt) {
                bf16x8 bfr = ldsW[base + ((nt * 16 + r) ^ swz)];
                acc[nt] = __builtin_amdgcn_mfma_f32_16x16x32_bf16(bfr, af[kk], acc[nt], 0, 0, 0);
            }
        }
    }

    if (EPI == 1) {                       // LN + ReLU
        float s = 0.f, q = 0.f;
        #pragma unroll
        for (int nt = 0; nt < NT; ++nt)
            #pragma unroll
            for (int i = 0; i < 4; ++i) { float v = acc[nt][i]; s += v; q += v * v; }
        s += __shfl_xor(s, 16); q += __shfl_xor(q, 16);
        s += __shfl_xor(s, 32); q += __shfl_xor(q, 32);
        float mean = s * (1.0f / 256.0f);
        float rstd = rsqrtf(q * (1.0f / 256.0f) - mean * mean + EPSV);
        #pragma unroll
        for (int nt = 0; nt < NT; ++nt) {
            float4 gg = *(const float4*)(g1 + nt * 16 + c4);
            float4 bb = *(const float4*)(b1 + nt * 16 + c4);
            bf16x4 st;
            st[0] = (bf16)fmaxf((acc[nt][0] - mean) * rstd * gg.x + bb.x, 0.f);
            st[1] = (bf16)fmaxf((acc[nt][1] - mean) * rstd * gg.y + bb.y, 0.f);
            st[2] = (bf16)fmaxf((acc[nt][2] - mean) * rstd * gg.z + bb.z, 0.f);
            st[3] = (bf16)fmaxf((acc[nt][3] - mean) * rstd * gg.w + bb.w, 0.f);
            *(bf16x4*)(O0 + row * 256 + nt * 16 + c4) = st;
        }
    } else if (EPI == 2) {                // residual in-place
        #pragma unroll
        for (int nt = 0; nt < NT; ++nt) {
            bf16* p = O0 + row * 256 + nt * 16 + c4;
            bf16x4 hv = *(const bf16x4*)p;
            bf16x4 st;
            #pragma unroll
            for (int i = 0; i < 4; ++i) st[i] = (bf16)(acc[nt][i] + (float)hv[i]);
            *(bf16x4*)p = st;
        }
    } else if (EPI == 3) {                // in_proj: y=0 x-half plain, y=1 z-half silu
        const int dosilu = (colblk >= 256);
        bf16* dst = dosilu ? O1 : O0;
        #pragma unroll
        for (int nt = 0; nt < NT; ++nt) {
            bf16x4 st;
            #pragma unroll
            for (int i = 0; i < 4; ++i) {
                float v = acc[nt][i];
                if (dosilu) v = silu_f(v);
                st[i] = (bf16)v;
            }
            *(bf16x4*)(dst + row * 256 + nt * 16 + c4) = st;
        }
    } else {                              // EPI 4: +h, LN, fp32 out
        #pragma unroll
        for (int nt = 0; nt < NT; ++nt) {
            bf16x4 hv = *(const bf16x4*)(O0 + row * 256 + nt * 16 + c4);
            #pragma unroll
            for (int i = 0; i < 4; ++i) acc[nt][i] += (float)hv[i];
        }
        float s = 0.f, q = 0.f;
        #pragma unroll
        for (int nt = 0; nt < NT; ++nt)
            #pragma unroll
            for (int i = 0; i < 4; ++i) { float v = acc[nt][i]; s += v; q += v * v; }
        s += __shfl_xor(s, 16); q += __shfl_xor(q, 16);
        s += __shfl_xor(s, 32); q += __shfl_xor(q, 32);
        float mean = s * (1.0f / 256.0f);
        float rstd = rsqrtf(q * (1.0f / 256.0f) - mean * mean + EPSV);
        #pragma unroll
        for (int nt = 0; nt < NT; ++nt) {
            float4 gg = *(const float4*)(g1 + nt * 16 + c4);
            float4 bb = *(const float4*)(b1 + nt * 16 + c4);
            float4 o;
            o.x = (acc[nt][0] - mean) * rstd * gg.x + bb.x;
            o.y = (acc[nt][1] - mean) * rstd * gg.y + bb.y;
            o.z = (acc[nt][2] - mean) * rstd * gg.z + bb.z;
            o.w = (acc[nt][3] - mean) * rstd * gg.w + bb.w;
            *(float4*)(Of + row * 256 + nt * 16 + c4) = o;
        }
    }
}

// ---------------------------------------------------------------------------
// pass 1: conv(K=4)+SiLU+local EMA inside a 64-step chunk; emit chunk-final only.
__global__ void pass1_k(const bf16* __restrict__ xc,
                        const float* __restrict__ cw, const float* __restrict__ cb,
                        float* __restrict__ cfin)
{
    const int d0 = threadIdx.x * 2;
    const int c = blockIdx.x, b = blockIdx.y;
    const int t0 = c * CH;
    const float w00=cw[d0*4+0], w01=cw[d0*4+1], w02=cw[d0*4+2], w03=cw[d0*4+3];
    const float w10=cw[d0*4+4], w11=cw[d0*4+5], w12=cw[d0*4+6], w13=cw[d0*4+7];
    const float bb0 = cb[d0], bb1 = cb[d0+1];
    const float a0 = decay_of(d0), a1 = decay_of(d0+1);
    const size_t base = (size_t)b * TT * 256 + d0;
    float x0m1=0,x0m2=0,x0m3=0, x1m1=0,x1m2=0,x1m3=0;
    if (t0 >= 1) { bf16x2 p = *(const bf16x2*)(xc + base + (size_t)(t0-1)*256); x0m1=(float)p[0]; x1m1=(float)p[1]; }
    if (t0 >= 2) { bf16x2 p = *(const bf16x2*)(xc + base + (size_t)(t0-2)*256); x0m2=(float)p[0]; x1m2=(float)p[1]; }
    if (t0 >= 3) { bf16x2 p = *(const bf16x2*)(xc + base + (size_t)(t0-3)*256); x0m3=(float)p[0]; x1m3=(float)p[1]; }
    float h0 = 0.f, h1 = 0.f;
    for (int t = t0; t < t0 + CH; ++t) {
        bf16x2 p = *(const bf16x2*)(xc + base + (size_t)t * 256);
        float xa = (float)p[0], xb = (float)p[1];
        float v0 = w03*xa + w02*x0m1 + w01*x0m2 + w00*x0m3 + bb0;
        float v1 = w13*xb + w12*x1m1 + w11*x1m2 + w10*x1m3 + bb1;
        h0 = a0*h0 + (1.f-a0)*silu_f(v0);
        h1 = a1*h1 + (1.f-a1)*silu_f(v1);
        x0m3=x0m2; x0m2=x0m1; x0m1=xa;
        x1m3=x1m2; x1m2=x1m1; x1m1=xb;
    }
    *(float2*)(cfin + ((size_t)b*NC + c)*256 + d0) = make_float2(h0, h1);
}

// pass 2: per-(b,d) carry recurrence over the 64 chunk finals.
__global__ void scan2_k(const float* __restrict__ cfin, float* __restrict__ cin)
{
    const int d = threadIdx.x, b = blockIdx.x;
    float a = decay_of(d);
    float aC = a;
    #pragma unroll
    for (int j = 0; j < 6; ++j) aC *= aC;   // a^64
    float H = 0.f;
    for (int c = 0; c < NC; ++c) {
        size_t o = ((size_t)b * NC + c) * 256 + d;
        cin[o] = H;
        H = aC * H + cfin[o];
    }
}

// pass 3: recompute conv+SiLU+EMA with exact carry-in; u = hi * sz; u aliases sz.
__global__ void pass3_k(const bf16* __restrict__ xc, const float* __restrict__ cin,
                        const float* __restrict__ cw, const float* __restrict__ cb,
                        bf16* __restrict__ szu)
{
    const int d0 = threadIdx.x * 2;
    const int c = blockIdx.x, b = blockIdx.y;
    const int t0 = c * CH;
    const float w00=cw[d0*4+0], w01=cw[d0*4+1], w02=cw[d0*4+2], w03=cw[d0*4+3];
    const float w10=cw[d0*4+4], w11=cw[d0*4+5], w12=cw[d0*4+6], w13=cw[d0*4+7];
    const float bb0 = cb[d0], bb1 = cb[d0+1];
    const float a0 = decay_of(d0), a1 = decay_of(d0+1);
    const size_t base = (size_t)b * TT * 256 + d0;
    float2 Hc = *(const float2*)(cin + ((size_t)b*NC + c)*256 + d0);
    float h0 = Hc.x, h1 = Hc.y;
    float x0m1=0,x0m2=0,x0m3=0, x1m1=0,x1m2=0,x1m3=0;
    if (t0 >= 1) { bf16x2 p = *(const bf16x2*)(xc + base + (size_t)(t0-1)*256); x0m1=(float)p[0]; x1m1=(float)p[1]; }
    if (t0 >= 2) { bf16x2 p = *(const bf16x2*)(xc + base + (size_t)(t0-2)*256); x0m2=(float)p[0]; x1m2=(float)p[1]; }
    if (t0 >= 3) { bf16x2 p = *(const bf16x2*)(xc + base + (size_t)(t0-3)*256); x0m3=(float)p[0]; x1m3=(float)p[1]; }
    for (int t = t0; t < t0 + CH; ++t) {
        bf16x2 p = *(const bf16x2*)(xc + base + (size_t)t * 256);
        float xa = (float)p[0], xb = (float)p[1];
        float v0 = w03*xa + w02*x0m1 + w01*x0m2 + w00*x0m3 + bb0;
        float v1 = w13*xb + w12*x1m1 + w11*x1m2 + w10*x1m3 + bb1;
        h0 = a0*h0 + (1.f-a0)*silu_f(v0);
        h1 = a1*h1 + (1.f-a1)*silu_f(v1);
        x0m3=x0m2; x0m2=x0m1; x0m1=xa;
        x1m3=x1m2; x1m2=x1m1; x1m1=xb;
        bf16* up = szu + base + (size_t)t * 256;
        bf16x2 sp = *(const bf16x2*)up;
        bf16x2 st;
        st[0] = (bf16)(h0 * (float)sp[0]);
        st[1] = (bf16)(h1 * (float)sp[1]);
        *(bf16x2*)up = st;
    }
}

// ---------------------------------------------------------------------------
extern "C" void kernel_launch(void* const* d_in, const int* in_sizes, int n_in,
                              void* d_out, int out_size, void* d_ws, size_t ws_size,
                              hipStream_t stream)
{
    (void)in_sizes; (void)n_in; (void)out_size;
    const float* x        = (const float*)d_in[0];
    const float* enc_w    = (const float*)d_in[1];
    const float* enc_b    = (const float*)d_in[2];
    const float* enc_ln_g = (const float*)d_in[3];
    const float* enc_ln_b = (const float*)d_in[4];
    const float* in_proj_w  = (const float*)d_in[5];
    const float* in_proj_b  = (const float*)d_in[6];
    const float* conv_w     = (const float*)d_in[7];
    const float* conv_b     = (const float*)d_in[8];
    const float* out_proj_w = (const float*)d_in[9];
    const float* out_proj_b = (const float*)d_in[10];
    const float* lnf_g      = (const float*)d_in[11];
    const float* lnf_b      = (const float*)d_in[12];

    // workspace: h (64MiB) | sz/u (64MiB) | wenc 128K | winp 512K | woutp 256K | cfin 2M | cin 2M
    if (ws_size < 139329536u) return;
    char* ws = (char*)d_ws;
    bf16*  h     = (bf16*)(ws);
    bf16*  szu   = (bf16*)(ws + 67108864);
    bf16*  wenc  = (bf16*)(ws + 134217728);
    bf16*  winp  = (bf16*)(ws + 134217728 + 131072);
    bf16*  woutp = (bf16*)(ws + 134217728 + 131072 + 524288);
    float* cfin  = (float*)(ws + 134217728 + 917504);
    float* cin   = (float*)(ws + 134217728 + 917504 + 2097152);
    bf16*  xc    = (bf16*)d_out;   // first 64 MiB of d_out as bf16 scratch

    cvtw_k<<<dim3(448), dim3(1024), 0, stream>>>(enc_w, in_proj_w, out_proj_w,
                                                 wenc, winp, woutp);

    dim3 gblk(512);
    // encoder: h = relu(LN(x @ enc_w^T + enc_b))
    gemm_k<1, 1><<<dim3(1024, 1), gblk, 0, stream>>>(x, wenc, enc_b,
                                                    enc_ln_g, enc_ln_b, h, nullptr, nullptr);
    for (int l = 0; l < LL; ++l) {
        // xc = h @ Wx^T + bx ; sz = silu(h @ Wz^T + bz)   [2 x 256-col y-blocks]
        gemm_k<0, 3><<<dim3(1024, 2), gblk, 0, stream>>>(h, winp + (size_t)l * 512 * 256,
                                                        in_proj_b + l * 512, nullptr, nullptr,
                                                        xc, szu, nullptr);
        pass1_k<<<dim3(NC, BB), dim3(128), 0, stream>>>(xc, conv_w + l * DD * 4,
                                                        conv_b + l * DD, cfin);
        scan2_k<<<dim3(BB), dim3(256), 0, stream>>>(cfin, cin);
        pass3_k<<<dim3(NC, BB), dim3(128), 0, stream>>>(xc, cin, conv_w + l * DD * 4,
                                                        conv_b + l * DD, szu);
        if (l == 0) {
            // h += u @ out_proj_w[0]^T + b
            gemm_k<0, 2><<<dim3(1024, 1), gblk, 0, stream>>>(szu, woutp,
                                                            out_proj_b, nullptr, nullptr,
                                                            h, nullptr, nullptr);
        } else {
            // out = LN(h + u @ out_proj_w[1]^T + b) -> fp32 d_out
            gemm_k<0, 4><<<dim3(1024, 1), gblk, 0, stream>>>(szu, woutp + (size_t)256 * 256,
                                                            out_proj_b + 256, lnf_g, lnf_b,
                                                            h, nullptr, (float*)d_out);
        }
    }
}

// Round 8
// 540.719 us; speedup vs baseline: 2.2440x; 1.0979x over previous
//
#include <hip/hip_runtime.h>
#include <hip/hip_bf16.h>
#include <math.h>

#define BB 32
#define TT 4096
#define DD 256
#define LL 2
#define NC 64          // number of time chunks for the scan
#define CH 64          // chunk length (NC*CH == TT)
#define MM (BB*TT)     // 131072 rows
#define EPSV 1e-5f

typedef __bf16 bf16;
typedef __attribute__((ext_vector_type(8))) __bf16 bf16x8;
typedef __attribute__((ext_vector_type(4))) __bf16 bf16x4;
typedef __attribute__((ext_vector_type(2))) __bf16 bf16x2;
typedef __attribute__((ext_vector_type(4))) float f32x4;

// ---------------------------------------------------------------------------
__device__ __forceinline__ float decay_of(int d) {
    const float l0 = 2.302585092994046f;      // log(10)
    const float l1 = 7.6009024595420815f;     // log(2000)
    float lt = l0 + (float)d * (l1 - l0) * (1.0f / 255.0f);
    return expf(-expf(-lt));
}
__device__ __forceinline__ float silu_f(float v) { return v / (1.0f + expf(-v)); }

// ---------------------------------------------------------------------------
// one-shot fp32 -> bf16 conversion of all three weight tensors
__global__ void cvtw_k(const float* __restrict__ we, const float* __restrict__ wi,
                       const float* __restrict__ wo, bf16* __restrict__ de,
                       bf16* __restrict__ di, bf16* __restrict__ dk)
{
    int i = blockIdx.x * 1024 + threadIdx.x;            // 458752 total
    if (i < 65536)            de[i] = (bf16)we[i];
    else if (i < 327680)      di[i - 65536] = (bf16)wi[i - 65536];
    else if (i < 458752)      dk[i - 327680] = (bf16)wo[i - 327680];
}

// ---------------------------------------------------------------------------
// GEMM: C[64 rows x 256 cols] = A[M x 256] * W^T + bias, one tile/block.
// 256 threads / 4 waves, wave owns 16 A-rows x 256 cols.
// Swapped-operand MFMA: D "row" = W-col (lane>>4)*4+i, D "col" = A-row (lane&15).
//
// REGISTER/OCCUPANCY MODEL (rounds 1-7 evidence):
//  - CSV VGPR_Count excludes AGPRs; true footprint ~= VGPR + 64 AGPR (acc[16]).
//  - MINW>=4 caps make hipcc sandbag to 48-64 VGPR and spill acc across the
//    stage barriers (R2/R5/R6: 2-6x HBM traffic). MINW<=2 never spilled.
//  - 512-thr blocks @ ~164 regs round down to 1 block/CU (R7: 20% occ).
//  => 256-thr blocks + launch_bounds(256,2): natural ~100+64 regs -> 3
//     waves/SIMD -> 3 blocks/CU = 12 waves, no spill. (R6 shape, R7 bounds.)
//
// K-split staging through a fixed 32 KiB LDS buffer (4 stages x 8 k-chunks).
// LDS fragment-major + XOR swizzle: unit idx = kc_local*256 + (n ^ (kcg&15));
// staging writes and MFMA reads spread over banks (0 conflicts, verified R4-R7).
// EPI 1: rowwise LN+ReLU -> O0 bf16     (encoder)
// EPI 2: O0 += acc (in-place bf16 h)
// EPI 3: y=0 -> O0 plain (x half); y=1 -> silu -> O1 (z half)   (in_proj)
// EPI 4: acc += O0(h); rowwise LN -> Of fp32   (out_proj l1 + final LN)
template<int SRCF32, int EPI>
__global__ __launch_bounds__(256, 2)
void gemm_k(const void* __restrict__ Asrc,
            const bf16* __restrict__ W,
            const float* __restrict__ bias,
            const float* __restrict__ g1, const float* __restrict__ b1,
            bf16* __restrict__ O0, bf16* __restrict__ O1,
            float* __restrict__ Of)
{
    constexpr int NT = 16;                    // 256 cols / 16
    constexpr int KCS = 8;                    // 16B k-chunks per stage
    constexpr int NSTAGE = 4;                 // stages to cover K=256
    constexpr int KKS = 2;                    // kk (32-wide K steps) per stage
    __shared__ bf16x8 ldsW[2048];             // 32 KiB

    const int tid = threadIdx.x;
    const int colblk = blockIdx.y * 256;
    const bf16* Wblk = W + (size_t)colblk * 256;

    const int wave = tid >> 6, lane = tid & 63;
    const int r = lane & 15, g4 = lane >> 4;
    const int c4 = g4 * 4;                    // first of 4 consecutive cols
    const size_t row = (size_t)blockIdx.x * 64 + wave * 16 + r;

    // ---- issue A-fragment loads first (latency hides under staging) ----
    bf16x8 af[8];
    if (SRCF32) {
        const float* ap0 = (const float*)Asrc + row * 256;
        #pragma unroll
        for (int kk = 0; kk < 8; ++kk) {
            const float* ap = ap0 + kk * 32 + g4 * 8;
            float4 f0 = *(const float4*)ap;
            float4 f1 = *(const float4*)(ap + 4);
            bf16x8 t;
            t[0]=(bf16)f0.x; t[1]=(bf16)f0.y; t[2]=(bf16)f0.z; t[3]=(bf16)f0.w;
            t[4]=(bf16)f1.x; t[5]=(bf16)f1.y; t[6]=(bf16)f1.z; t[7]=(bf16)f1.w;
            af[kk] = t;
        }
    } else {
        const bf16* ap0 = (const bf16*)Asrc + row * 256;
        #pragma unroll
        for (int kk = 0; kk < 8; ++kk)
            af[kk] = *(const bf16x8*)(ap0 + kk * 32 + g4 * 8);
    }

    f32x4 acc[NT];
    #pragma unroll
    for (int nt = 0; nt < NT; ++nt) {
        float4 bv = *(const float4*)(bias + colblk + nt * 16 + c4);
        acc[nt] = (f32x4){bv.x, bv.y, bv.z, bv.w};
    }

    // ---- K-split staged main loop ----
    #pragma unroll
    for (int s = 0; s < NSTAGE; ++s) {
        if (s) __syncthreads();               // readers of previous stage done
        const int sBase = s * KCS;
        #pragma unroll
        for (int i = 0; i < 8; ++i) {         // 2048 units / 256 threads
            int idx = tid + i * 256;
            int n   = idx >> 3;               // W-col within tile (0..255)
            int kc  = idx & 7;                // local 16B k-chunk
            int kcg = sBase + kc;             // global k-chunk
            ldsW[kc * 256 + (n ^ (kcg & 15))] =
                *(const bf16x8*)(Wblk + n * 256 + kcg * 8);
        }
        __syncthreads();
        #pragma unroll
        for (int kk = s * KKS; kk < (s + 1) * KKS; ++kk) {
            const int kcg = kk * 4 + g4;
            const int base = (kcg - sBase) * 256;
            const int swz = kcg & 15;
            #pragma unroll
            for (int nt = 0; nt < NT; ++nt) {
                bf16x8 bfr = ldsW[base + ((nt * 16 + r) ^ swz)];
                acc[nt] = __builtin_amdgcn_mfma_f32_16x16x32_bf16(bfr, af[kk], acc[nt], 0, 0, 0);
            }
        }
    }

    if (EPI == 1) {                       // LN + ReLU
        float s = 0.f, q = 0.f;
        #pragma unroll
        for (int nt = 0; nt < NT; ++nt)
            #pragma unroll
            for (int i = 0; i < 4; ++i) { float v = acc[nt][i]; s += v; q += v * v; }
        s += __shfl_xor(s, 16); q += __shfl_xor(q, 16);
        s += __shfl_xor(s, 32); q += __shfl_xor(q, 32);
        float mean = s * (1.0f / 256.0f);
        float rstd = rsqrtf(q * (1.0f / 256.0f) - mean * mean + EPSV);
        #pragma unroll
        for (int nt = 0; nt < NT; ++nt) {
            float4 gg = *(const float4*)(g1 + nt * 16 + c4);
            float4 bb = *(const float4*)(b1 + nt * 16 + c4);
            bf16x4 st;
            st[0] = (bf16)fmaxf((acc[nt][0] - mean) * rstd * gg.x + bb.x, 0.f);
            st[1] = (bf16)fmaxf((acc[nt][1] - mean) * rstd * gg.y + bb.y, 0.f);
            st[2] = (bf16)fmaxf((acc[nt][2] - mean) * rstd * gg.z + bb.z, 0.f);
            st[3] = (bf16)fmaxf((acc[nt][3] - mean) * rstd * gg.w + bb.w, 0.f);
            *(bf16x4*)(O0 + row * 256 + nt * 16 + c4) = st;
        }
    } else if (EPI == 2) {                // residual in-place
        #pragma unroll
        for (int nt = 0; nt < NT; ++nt) {
            bf16* p = O0 + row * 256 + nt * 16 + c4;
            bf16x4 hv = *(const bf16x4*)p;
            bf16x4 st;
            #pragma unroll
            for (int i = 0; i < 4; ++i) st[i] = (bf16)(acc[nt][i] + (float)hv[i]);
            *(bf16x4*)p = st;
        }
    } else if (EPI == 3) {                // in_proj: y=0 x-half plain, y=1 z-half silu
        const int dosilu = (colblk >= 256);
        bf16* dst = dosilu ? O1 : O0;
        #pragma unroll
        for (int nt = 0; nt < NT; ++nt) {
            bf16x4 st;
            #pragma unroll
            for (int i = 0; i < 4; ++i) {
                float v = acc[nt][i];
                if (dosilu) v = silu_f(v);
                st[i] = (bf16)v;
            }
            *(bf16x4*)(dst + row * 256 + nt * 16 + c4) = st;
        }
    } else {                              // EPI 4: +h, LN, fp32 out
        #pragma unroll
        for (int nt = 0; nt < NT; ++nt) {
            bf16x4 hv = *(const bf16x4*)(O0 + row * 256 + nt * 16 + c4);
            #pragma unroll
            for (int i = 0; i < 4; ++i) acc[nt][i] += (float)hv[i];
        }
        float s = 0.f, q = 0.f;
        #pragma unroll
        for (int nt = 0; nt < NT; ++nt)
            #pragma unroll
            for (int i = 0; i < 4; ++i) { float v = acc[nt][i]; s += v; q += v * v; }
        s += __shfl_xor(s, 16); q += __shfl_xor(q, 16);
        s += __shfl_xor(s, 32); q += __shfl_xor(q, 32);
        float mean = s * (1.0f / 256.0f);
        float rstd = rsqrtf(q * (1.0f / 256.0f) - mean * mean + EPSV);
        #pragma unroll
        for (int nt = 0; nt < NT; ++nt) {
            float4 gg = *(const float4*)(g1 + nt * 16 + c4);
            float4 bb = *(const float4*)(b1 + nt * 16 + c4);
            float4 o;
            o.x = (acc[nt][0] - mean) * rstd * gg.x + bb.x;
            o.y = (acc[nt][1] - mean) * rstd * gg.y + bb.y;
            o.z = (acc[nt][2] - mean) * rstd * gg.z + bb.z;
            o.w = (acc[nt][3] - mean) * rstd * gg.w + bb.w;
            *(float4*)(Of + row * 256 + nt * 16 + c4) = o;
        }
    }
}

// ---------------------------------------------------------------------------
// pass 1: conv(K=4)+SiLU+local EMA inside a 64-step chunk; emit chunk-final only.
__global__ void pass1_k(const bf16* __restrict__ xc,
                        const float* __restrict__ cw, const float* __restrict__ cb,
                        float* __restrict__ cfin)
{
    const int d0 = threadIdx.x * 2;
    const int c = blockIdx.x, b = blockIdx.y;
    const int t0 = c * CH;
    const float w00=cw[d0*4+0], w01=cw[d0*4+1], w02=cw[d0*4+2], w03=cw[d0*4+3];
    const float w10=cw[d0*4+4], w11=cw[d0*4+5], w12=cw[d0*4+6], w13=cw[d0*4+7];
    const float bb0 = cb[d0], bb1 = cb[d0+1];
    const float a0 = decay_of(d0), a1 = decay_of(d0+1);
    const size_t base = (size_t)b * TT * 256 + d0;
    float x0m1=0,x0m2=0,x0m3=0, x1m1=0,x1m2=0,x1m3=0;
    if (t0 >= 1) { bf16x2 p = *(const bf16x2*)(xc + base + (size_t)(t0-1)*256); x0m1=(float)p[0]; x1m1=(float)p[1]; }
    if (t0 >= 2) { bf16x2 p = *(const bf16x2*)(xc + base + (size_t)(t0-2)*256); x0m2=(float)p[0]; x1m2=(float)p[1]; }
    if (t0 >= 3) { bf16x2 p = *(const bf16x2*)(xc + base + (size_t)(t0-3)*256); x0m3=(float)p[0]; x1m3=(float)p[1]; }
    float h0 = 0.f, h1 = 0.f;
    for (int t = t0; t < t0 + CH; ++t) {
        bf16x2 p = *(const bf16x2*)(xc + base + (size_t)t * 256);
        float xa = (float)p[0], xb = (float)p[1];
        float v0 = w03*xa + w02*x0m1 + w01*x0m2 + w00*x0m3 + bb0;
        float v1 = w13*xb + w12*x1m1 + w11*x1m2 + w10*x1m3 + bb1;
        h0 = a0*h0 + (1.f-a0)*silu_f(v0);
        h1 = a1*h1 + (1.f-a1)*silu_f(v1);
        x0m3=x0m2; x0m2=x0m1; x0m1=xa;
        x1m3=x1m2; x1m2=x1m1; x1m1=xb;
    }
    *(float2*)(cfin + ((size_t)b*NC + c)*256 + d0) = make_float2(h0, h1);
}

// pass 2: per-(b,d) carry recurrence over the 64 chunk finals.
__global__ void scan2_k(const float* __restrict__ cfin, float* __restrict__ cin)
{
    const int d = threadIdx.x, b = blockIdx.x;
    float a = decay_of(d);
    float aC = a;
    #pragma unroll
    for (int j = 0; j < 6; ++j) aC *= aC;   // a^64
    float H = 0.f;
    for (int c = 0; c < NC; ++c) {
        size_t o = ((size_t)b * NC + c) * 256 + d;
        cin[o] = H;
        H = aC * H + cfin[o];
    }
}

// pass 3: recompute conv+SiLU+EMA with exact carry-in; u = hi * sz; u aliases sz.
__global__ void pass3_k(const bf16* __restrict__ xc, const float* __restrict__ cin,
                        const float* __restrict__ cw, const float* __restrict__ cb,
                        bf16* __restrict__ szu)
{
    const int d0 = threadIdx.x * 2;
    const int c = blockIdx.x, b = blockIdx.y;
    const int t0 = c * CH;
    const float w00=cw[d0*4+0], w01=cw[d0*4+1], w02=cw[d0*4+2], w03=cw[d0*4+3];
    const float w10=cw[d0*4+4], w11=cw[d0*4+5], w12=cw[d0*4+6], w13=cw[d0*4+7];
    const float bb0 = cb[d0], bb1 = cb[d0+1];
    const float a0 = decay_of(d0), a1 = decay_of(d0+1);
    const size_t base = (size_t)b * TT * 256 + d0;
    float2 Hc = *(const float2*)(cin + ((size_t)b*NC + c)*256 + d0);
    float h0 = Hc.x, h1 = Hc.y;
    float x0m1=0,x0m2=0,x0m3=0, x1m1=0,x1m2=0,x1m3=0;
    if (t0 >= 1) { bf16x2 p = *(const bf16x2*)(xc + base + (size_t)(t0-1)*256); x0m1=(float)p[0]; x1m1=(float)p[1]; }
    if (t0 >= 2) { bf16x2 p = *(const bf16x2*)(xc + base + (size_t)(t0-2)*256); x0m2=(float)p[0]; x1m2=(float)p[1]; }
    if (t0 >= 3) { bf16x2 p = *(const bf16x2*)(xc + base + (size_t)(t0-3)*256); x0m3=(float)p[0]; x1m3=(float)p[1]; }
    for (int t = t0; t < t0 + CH; ++t) {
        bf16x2 p = *(const bf16x2*)(xc + base + (size_t)t * 256);
        float xa = (float)p[0], xb = (float)p[1];
        float v0 = w03*xa + w02*x0m1 + w01*x0m2 + w00*x0m3 + bb0;
        float v1 = w13*xb + w12*x1m1 + w11*x1m2 + w10*x1m3 + bb1;
        h0 = a0*h0 + (1.f-a0)*silu_f(v0);
        h1 = a1*h1 + (1.f-a1)*silu_f(v1);
        x0m3=x0m2; x0m2=x0m1; x0m1=xa;
        x1m3=x1m2; x1m2=x1m1; x1m1=xb;
        bf16* up = szu + base + (size_t)t * 256;
        bf16x2 sp = *(const bf16x2*)up;
        bf16x2 st;
        st[0] = (bf16)(h0 * (float)sp[0]);
        st[1] = (bf16)(h1 * (float)sp[1]);
        *(bf16x2*)up = st;
    }
}

// ---------------------------------------------------------------------------
extern "C" void kernel_launch(void* const* d_in, const int* in_sizes, int n_in,
                              void* d_out, int out_size, void* d_ws, size_t ws_size,
                              hipStream_t stream)
{
    (void)in_sizes; (void)n_in; (void)out_size;
    const float* x        = (const float*)d_in[0];
    const float* enc_w    = (const float*)d_in[1];
    const float* enc_b    = (const float*)d_in[2];
    const float* enc_ln_g = (const float*)d_in[3];
    const float* enc_ln_b = (const float*)d_in[4];
    const float* in_proj_w  = (const float*)d_in[5];
    const float* in_proj_b  = (const float*)d_in[6];
    const float* conv_w     = (const float*)d_in[7];
    const float* conv_b     = (const float*)d_in[8];
    const float* out_proj_w = (const float*)d_in[9];
    const float* out_proj_b = (const float*)d_in[10];
    const float* lnf_g      = (const float*)d_in[11];
    const float* lnf_b      = (const float*)d_in[12];

    // workspace: h (64MiB) | sz/u (64MiB) | wenc 128K | winp 512K | woutp 256K | cfin 2M | cin 2M
    if (ws_size < 139329536u) return;
    char* ws = (char*)d_ws;
    bf16*  h     = (bf16*)(ws);
    bf16*  szu   = (bf16*)(ws + 67108864);
    bf16*  wenc  = (bf16*)(ws + 134217728);
    bf16*  winp  = (bf16*)(ws + 134217728 + 131072);
    bf16*  woutp = (bf16*)(ws + 134217728 + 131072 + 524288);
    float* cfin  = (float*)(ws + 134217728 + 917504);
    float* cin   = (float*)(ws + 134217728 + 917504 + 2097152);
    bf16*  xc    = (bf16*)d_out;   // first 64 MiB of d_out as bf16 scratch

    cvtw_k<<<dim3(448), dim3(1024), 0, stream>>>(enc_w, in_proj_w, out_proj_w,
                                                 wenc, winp, woutp);

    dim3 gblk(256);
    // encoder: h = relu(LN(x @ enc_w^T + enc_b))
    gemm_k<1, 1><<<dim3(2048, 1), gblk, 0, stream>>>(x, wenc, enc_b,
                                                    enc_ln_g, enc_ln_b, h, nullptr, nullptr);
    for (int l = 0; l < LL; ++l) {
        // xc = h @ Wx^T + bx ; sz = silu(h @ Wz^T + bz)   [2 x 256-col y-blocks]
        gemm_k<0, 3><<<dim3(2048, 2), gblk, 0, stream>>>(h, winp + (size_t)l * 512 * 256,
                                                        in_proj_b + l * 512, nullptr, nullptr,
                                                        xc, szu, nullptr);
        pass1_k<<<dim3(NC, BB), dim3(128), 0, stream>>>(xc, conv_w + l * DD * 4,
                                                        conv_b + l * DD, cfin);
        scan2_k<<<dim3(BB), dim3(256), 0, stream>>>(cfin, cin);
        pass3_k<<<dim3(NC, BB), dim3(128), 0, stream>>>(xc, cin, conv_w + l * DD * 4,
                                                        conv_b + l * DD, szu);
        if (l == 0) {
            // h += u @ out_proj_w[0]^T + b
            gemm_k<0, 2><<<dim3(2048, 1), gblk, 0, stream>>>(szu, woutp,
                                                            out_proj_b, nullptr, nullptr,
                                                            h, nullptr, nullptr);
        } else {
            // out = LN(h + u @ out_proj_w[1]^T + b) -> fp32 d_out
            gemm_k<0, 4><<<dim3(2048, 1), gblk, 0, stream>>>(szu, woutp + (size_t)256 * 256,
                                                            out_proj_b + 256, lnf_g, lnf_b,
                                                            h, nullptr, (float*)d_out);
        }
    }
}